// Round 3
// baseline (492.503 us; speedup 1.0000x reference)
//
#include <hip/hip_runtime.h>
#include <hip/hip_bf16.h>

#define HIDDEN 512
#define ATT    128
#define NB     64
#define SL     2048
#define LN_EPS 1e-3f

typedef __attribute__((ext_vector_type(8))) short short8;
typedef __attribute__((ext_vector_type(4))) float f32x4;

__device__ __forceinline__ short f2bf(float f) {
    union { float f; unsigned u; } v; v.f = f;
    unsigned r = v.u + 0x7fffu + ((v.u >> 16) & 1u);   // RNE
    return (short)(r >> 16);
}
// packed f32x2 -> bf16x2 (v_cvt_pk_bf16_f32 on gfx950)
__device__ __forceinline__ unsigned pack2bf(float lo, float hi) {
    union { __hip_bfloat162 h; unsigned u; } v;
    v.h = __float22bfloat162_rn(make_float2(lo, hi));
    return v.u;
}
__device__ __forceinline__ float bflo(unsigned u) {
    union { unsigned x; float f; } v; v.x = u << 16; return v.f;
}
__device__ __forceinline__ float bfhi(unsigned u) {
    union { unsigned x; float f; } v; v.x = u & 0xffff0000u; return v.f;
}
__device__ __forceinline__ float tanh_fast(float x) {
    float cx = fminf(fmaxf(x, -15.f), 15.f);
    float e = __expf(2.f * cx);
    return (e - 1.f) * __builtin_amdgcn_rcpf(e + 1.f);
}

// ---- P0: Bp = bf16(W) pre-permuted into MFMA B-fragment order -------------
// Bp[((ks*8 + nt)*64 + lane)*8 + j] = bf16(W[h][a]),
//   h = ks*32 + (lane>>4)*8 + j, a = nt*16 + (lane&15)
__global__ void p0_wt(const float* __restrict__ W, short* __restrict__ Bp) {
    int idx = blockIdx.x * 256 + threadIdx.x;   // 65536 total
    int j = idx & 7, lane = (idx >> 3) & 63, nt = (idx >> 9) & 7, ks = idx >> 12;
    int a = nt * 16 + (lane & 15);
    int h = ks * 32 + ((lane >> 4) << 3) + j;
    Bp[idx] = f2bf(W[h * ATT + a]);
}

// ---- P1: h_att = bf16(h @ W) (fragment-permuted) + per-wave ctx partials --
// 1024 blocks x 256 thr. ZERO __syncthreads: each wave stages its OWN 32 rows
// into a private double-buffered LDS region (2x4KB), so all ordering is
// wave-local vmcnt/lgkmcnt. 12 independent wave-pipelines/CU hide latency.
//  - staging loads coalesced float4 (4 rows x 256B per instruction)
//  - LDS XOR-swizzle: 16B-block (col4>>1)^(row&7) -> reads/writes conflict-free
//  - B from pre-permuted Bp (coalesced 1KB/wave L2 hits)
//  - ctx column sums from staged fp32 regs (shfl over lane bits 4,5)
__launch_bounds__(256, 3)
__global__ void p1_gemm_ctx(const float* __restrict__ hidden, const short* __restrict__ Bp,
                            short* __restrict__ h_att, float* __restrict__ ctx_part) {
    __shared__ __align__(16) short As[4][2][32 * 64];   // 32 KB, [wave][buf]

    int t = threadIdx.x;
    int wave = t >> 6, lane = t & 63, quad = lane >> 4, cb = lane & 15;
    int row0 = blockIdx.x * 128 + wave * 32;

    f32x4 acc[2][8];
    #pragma unroll
    for (int mt = 0; mt < 2; ++mt)
        #pragma unroll
        for (int nt = 0; nt < 8; ++nt)
            acc[mt][nt] = (f32x4){0.f, 0.f, 0.f, 0.f};

    int lrow = lane >> 4;      // 0..3
    int col4 = lane & 15;      // float4 index within 64-wide chunk
    const float* sbase = hidden + (size_t)(row0 + lrow) * HIDDEN + col4 * 4;
    short (*my)[32 * 64] = As[wave];
    const short8* Bp8 = (const short8*)Bp + lane;

    float4 g[8];

    auto issue_loads = [&](int c) {
        const float* src = sbase + c * 64;
        #pragma unroll
        for (int p = 0; p < 8; ++p)
            g[p] = *(const float4*)(src + (size_t)p * 4 * HIDDEN);
    };

    auto pack_write = [&](int c, int buf) {
        float s[4] = {0.f, 0.f, 0.f, 0.f};
        #pragma unroll
        for (int p = 0; p < 8; ++p) {
            int row = p * 4 + lrow;                 // 0..31 within wave tile
            const float4 f = g[p];
            s[0] += f.x; s[1] += f.y; s[2] += f.z; s[3] += f.w;
            uint2 pk;
            pk.x = pack2bf(f.x, f.y);
            pk.y = pack2bf(f.z, f.w);
            int off = row * 64 + (((col4 >> 1) ^ (row & 7)) << 3) + ((col4 & 1) << 2);
            *(uint2*)&my[buf][off] = pk;
        }
        // reduce over lane bits 4,5 (the 4 row-subsets): cols (lane&15)*4..+3
        #pragma unroll
        for (int j = 0; j < 4; ++j) {
            s[j] += __shfl_xor(s[j], 16);
            s[j] += __shfl_xor(s[j], 32);
        }
        if (lane < 16) {
            float* cp = ctx_part + (size_t)(blockIdx.x * 4 + wave) * HIDDEN + c * 64 + lane * 4;
            *(float4*)cp = (float4){s[0], s[1], s[2], s[3]};
        }
    };

    auto compute = [&](int c, int buf) {
        int swz = cb & 7;
        #pragma unroll
        for (int s2 = 0; s2 < 2; ++s2) {
            int blk = ((s2 * 4 + quad) ^ swz) << 3;
            short8 a0 = *(const short8*)&my[buf][cb * 64 + blk];
            short8 a1 = *(const short8*)&my[buf][(cb + 16) * 64 + blk];
            int ks = c * 2 + s2;
            #pragma unroll
            for (int nt = 0; nt < 8; ++nt) {
                short8 b = Bp8[((size_t)ks * 8 + nt) * 64];
                acc[0][nt] = __builtin_amdgcn_mfma_f32_16x16x32_bf16(a0, b, acc[0][nt], 0, 0, 0);
                acc[1][nt] = __builtin_amdgcn_mfma_f32_16x16x32_bf16(a1, b, acc[1][nt], 0, 0, 0);
            }
        }
    };

    issue_loads(0);
    pack_write(0, 0);
    issue_loads(1);
    for (int c = 0; c < 8; ++c) {
        compute(c, c & 1);                       // ds_read current buffer + MFMA
        if (c < 7) pack_write(c + 1, (c + 1) & 1); // consume g (vmcnt counted wait)
        if (c < 6) issue_loads(c + 2);           // refill g for next iteration
    }

    // epilogue: fragment-permuted coalesced store, bf16 pair-packed
    uint2* hp = (uint2*)h_att;
    size_t base = (((size_t)blockIdx.x * 4 + wave) * 2) * 8 * 64 + lane;
    #pragma unroll
    for (int mt = 0; mt < 2; ++mt)
        #pragma unroll
        for (int nt = 0; nt < 8; ++nt) {
            uint2 p;
            p.x = pack2bf(acc[mt][nt][0], acc[mt][nt][1]);
            p.y = pack2bf(acc[mt][nt][2], acc[mt][nt][3]);
            hp[base + ((size_t)mt * 8 + nt) * 64] = p;
        }
}

// ---- P2: uatt[b][a] = (sum_chunks ctx_part / SL) . U[:,a] -----------------
__launch_bounds__(256)
__global__ void p2_uatt(const float* __restrict__ ctx_part, const float* __restrict__ U,
                        float* __restrict__ uatt) {
    int b = blockIdx.x, t = threadIdx.x;
    __shared__ float cs[HIDDEN];
    __shared__ float ds[256];
    float s0 = 0.f, s1 = 0.f;
    #pragma unroll 4
    for (int c = 0; c < 64; ++c) {
        const float* base = ctx_part + (size_t)(b * 64 + c) * HIDDEN;
        s0 += base[t];
        s1 += base[t + 256];
    }
    cs[t] = s0; cs[t + 256] = s1;
    __syncthreads();
    int a = t & 127, h0 = (t >> 7) * 256;
    float d = 0.f;
    #pragma unroll 8
    for (int h = 0; h < 256; ++h) d += cs[h0 + h] * U[(size_t)(h0 + h) * ATT + a];
    ds[t] = d;
    __syncthreads();
    if (t < 128) uatt[b * ATT + t] = (ds[t] + ds[t + 128]) * (1.f / SL);
}

// ---- P3: scores[r] = v . tanh(h_att[r] + uatt[b])  (fragment layout) ------
__launch_bounds__(256)
__global__ void p3_scores(const short* __restrict__ h_att, const float* __restrict__ v_a,
                          const float* __restrict__ uatt, float* __restrict__ scores) {
    int t = threadIdx.x, bx = blockIdx.x;
    int wave = t >> 6, lane = t & 63, quad = lane >> 4, cb = lane & 15;
    int b = bx >> 4;
    int row0 = bx * 128;

    float uv[8], vv[8];
    #pragma unroll
    for (int nt = 0; nt < 8; ++nt) {
        uv[nt] = uatt[b * ATT + nt * 16 + cb];
        vv[nt] = v_a[nt * 16 + cb];
    }

    const uint2* hp = (const uint2*)h_att;
    size_t base = (((size_t)bx * 4 + wave) * 2) * 8 * 64 + lane;

    #pragma unroll
    for (int mt = 0; mt < 2; ++mt) {
        uint2 f[8];
        #pragma unroll
        for (int nt = 0; nt < 8; ++nt) f[nt] = hp[base + ((size_t)mt * 8 + nt) * 64];
        float r[4] = {0.f, 0.f, 0.f, 0.f};
        #pragma unroll
        for (int nt = 0; nt < 8; ++nt) {
            r[0] += vv[nt] * tanh_fast(bflo(f[nt].x) + uv[nt]);
            r[1] += vv[nt] * tanh_fast(bfhi(f[nt].x) + uv[nt]);
            r[2] += vv[nt] * tanh_fast(bflo(f[nt].y) + uv[nt]);
            r[3] += vv[nt] * tanh_fast(bfhi(f[nt].y) + uv[nt]);
        }
        #pragma unroll
        for (int j = 0; j < 4; ++j) {
            r[j] += __shfl_xor(r[j], 1);
            r[j] += __shfl_xor(r[j], 2);
            r[j] += __shfl_xor(r[j], 4);
            r[j] += __shfl_xor(r[j], 8);
        }
        if (cb == 0) {
            #pragma unroll
            for (int j = 0; j < 4; ++j)
                scores[row0 + wave * 32 + mt * 16 + quad * 4 + j] = r[j];
        }
    }
}

// ---- P4: softmax over L (in place, in d_out's attn region) ----------------
__launch_bounds__(256)
__global__ void p4_softmax(float* __restrict__ attn) {
    int b = blockIdx.x, t = threadIdx.x;
    float* p = attn + b * SL;
    __shared__ float red[256];
    float v[8];
    float m = -1e30f;
    #pragma unroll
    for (int i = 0; i < 8; ++i) { v[i] = p[t + i * 256]; m = fmaxf(m, v[i]); }
    red[t] = m; __syncthreads();
    for (int s = 128; s > 0; s >>= 1) { if (t < s) red[t] = fmaxf(red[t], red[t + s]); __syncthreads(); }
    m = red[0]; __syncthreads();
    float sum = 0.f;
    #pragma unroll
    for (int i = 0; i < 8; ++i) { v[i] = __expf(v[i] - m); sum += v[i]; }
    red[t] = sum; __syncthreads();
    for (int s = 128; s > 0; s >>= 1) { if (t < s) red[t] += red[t + s]; __syncthreads(); }
    float inv = 1.f / red[0];
    #pragma unroll
    for (int i = 0; i < 8; ++i) p[t + i * 256] = v[i] * inv;
}

// ---- P5: attended partials: att_part[c][b][h] = sum_{l in chunk} attn*h ----
__launch_bounds__(256)
__global__ void p5_attended(const float* __restrict__ hidden, const float* __restrict__ attn,
                            float* __restrict__ att_part) {
    int b = blockIdx.y, c = blockIdx.x, t = threadIdx.x;
    __shared__ float w_s[128];
    __shared__ float4 red_s[128];
    if (t < 128) w_s[t] = attn[b * SL + c * 128 + t];
    __syncthreads();
    int cg = t & 127, half = t >> 7;
    const float* hp = hidden + ((size_t)b * SL + c * 128 + half * 64) * HIDDEN + cg * 4;
    float4 a = {0.f, 0.f, 0.f, 0.f};
    #pragma unroll 4
    for (int l = 0; l < 64; ++l) {
        float w = w_s[half * 64 + l];
        const float4 g = *(const float4*)(hp + (size_t)l * HIDDEN);
        a.x += w * g.x; a.y += w * g.y; a.z += w * g.z; a.w += w * g.w;
    }
    if (half) red_s[cg] = a;
    __syncthreads();
    if (!half) {
        float4 r = red_s[cg];
        a.x += r.x; a.y += r.y; a.z += r.z; a.w += r.w;
        *(float4*)(att_part + ((size_t)(c * NB + b)) * HIDDEN + cg * 4) = a;
    }
}

// ---- P6: reduce att_part chunks + LayerNorm -------------------------------
__launch_bounds__(256)
__global__ void p6_ln(const float* __restrict__ att_part, const float* __restrict__ gamma,
                      const float* __restrict__ beta, float* __restrict__ out) {
    int b = blockIdx.x, t = threadIdx.x;
    float x0 = 0.f, x1 = 0.f;
    #pragma unroll
    for (int c = 0; c < 16; ++c) {
        size_t base = (size_t)(c * NB + b) * HIDDEN;
        x0 += att_part[base + t];
        x1 += att_part[base + t + 256];
    }
    __shared__ float rs[256], rq[256];
    rs[t] = x0 + x1; rq[t] = x0 * x0 + x1 * x1;
    __syncthreads();
    for (int s = 128; s > 0; s >>= 1) {
        if (t < s) { rs[t] += rs[t + s]; rq[t] += rq[t + s]; }
        __syncthreads();
    }
    float mean = rs[0] * (1.f / HIDDEN);
    float var = rq[0] * (1.f / HIDDEN) - mean * mean;
    float r = rsqrtf(var + LN_EPS);
    out[b * HIDDEN + t]       = (x0 - mean) * r * gamma[t] + beta[t];
    out[b * HIDDEN + t + 256] = (x1 - mean) * r * gamma[t + 256] + beta[t + 256];
}

extern "C" void kernel_launch(void* const* d_in, const int* in_sizes, int n_in,
                              void* d_out, int out_size, void* d_ws, size_t ws_size,
                              hipStream_t stream) {
    const float* hidden = (const float*)d_in[0];
    const float* W      = (const float*)d_in[1];
    const float* U      = (const float*)d_in[2];
    const float* v_a    = (const float*)d_in[3];
    const float* gamma  = (const float*)d_in[4];
    const float* beta   = (const float*)d_in[5];

    float* out  = (float*)d_out;          // [64][512]
    float* attn = out + NB * HIDDEN;      // [64][2048] scores -> softmax in place

    // ws layout (every buffer fully written before read; no memset needed)
    short* h_att    = (short*)d_ws;                                        // [64*2048][128] bf16 (fragment-permuted)
    float* ctx_part = (float*)((char*)d_ws + (size_t)NB * SL * ATT * 2);   // [4096][512] per-wave
    float* att_part = ctx_part + (size_t)4096 * HIDDEN;                    // [16][64][512]
    float* uatt     = att_part + (size_t)16 * NB * HIDDEN;                 // [64][128]
    short* Bp       = (short*)(uatt + NB * ATT);                           // [16][8][64][8] bf16 (frag-permuted W)

    p0_wt<<<256, 256, 0, stream>>>(W, Bp);
    p1_gemm_ctx<<<(NB * SL) / 128, 256, 0, stream>>>(hidden, Bp, h_att, ctx_part);
    p2_uatt<<<NB, 256, 0, stream>>>(ctx_part, U, uatt);
    p3_scores<<<(NB * SL) / 128, 256, 0, stream>>>(h_att, v_a, uatt, attn);
    p4_softmax<<<NB, 256, 0, stream>>>(attn);
    p5_attended<<<dim3(16, NB), 256, 0, stream>>>(hidden, attn, att_part);
    p6_ln<<<NB, 256, 0, stream>>>(att_part, gamma, beta, out);
}

// Round 5
// 442.909 us; speedup vs baseline: 1.1120x; 1.1120x over previous
//
#include <hip/hip_runtime.h>
#include <hip/hip_bf16.h>

#define HIDDEN 512
#define ATT    128
#define NB     64
#define SL     2048
#define LN_EPS 1e-3f

typedef __attribute__((ext_vector_type(8))) short short8;
typedef __attribute__((ext_vector_type(4))) float f32x4;
typedef __attribute__((ext_vector_type(2))) unsigned ux2;

__device__ __forceinline__ short f2bf(float f) {
    union { float f; unsigned u; } v; v.f = f;
    unsigned r = v.u + 0x7fffu + ((v.u >> 16) & 1u);   // RNE
    return (short)(r >> 16);
}
__device__ __forceinline__ unsigned pack2bf(float lo, float hi) {
    union { __hip_bfloat162 h; unsigned u; } v;
    v.h = __float22bfloat162_rn(make_float2(lo, hi));
    return v.u;
}
__device__ __forceinline__ float bflo(unsigned u) {
    union { unsigned x; float f; } v; v.x = u << 16; return v.f;
}
__device__ __forceinline__ float bfhi(unsigned u) {
    union { unsigned x; float f; } v; v.x = u & 0xffff0000u; return v.f;
}
__device__ __forceinline__ float tanh_fast(float x) {
    float cx = fminf(fmaxf(x, -15.f), 15.f);
    float e = __expf(2.f * cx);
    return (e - 1.f) * __builtin_amdgcn_rcpf(e + 1.f);
}
__device__ __forceinline__ f32x4 nt_load4(const float* p) {
    return __builtin_nontemporal_load((const f32x4*)p);
}

// ---- P0: Bp = bf16(W) pre-permuted into MFMA B-fragment order -------------
// Bp[((ks*8 + nt)*64 + lane)*8 + j] = bf16(W[h][a]),
//   h = ks*32 + (lane>>4)*8 + j, a = nt*16 + (lane&15)
__global__ void p0_wt(const float* __restrict__ W, short* __restrict__ Bp) {
    int idx = blockIdx.x * 256 + threadIdx.x;   // 65536 total
    int j = idx & 7, lane = (idx >> 3) & 63, nt = (idx >> 9) & 7, ks = idx >> 12;
    int a = nt * 16 + (lane & 15);
    int h = ks * 32 + ((lane >> 4) << 3) + j;
    Bp[idx] = f2bf(W[h * ATT + a]);
}

// ---- P1: h_att = bf16(h @ W) (fragment-permuted) + per-wave ctx partials --
// 1024 blocks x 256 thr, zero __syncthreads (wave-private LDS dbuf).
// Key ordering fix: per iteration, B-fragment loads (L2) are issued BEFORE
// the next A-prefetch (HBM) so the in-order vmcnt queue never parks L2 hits
// behind a 900-cycle HBM round trip. A-stream + intermediate stores are
// non-temporal to keep Bp L2-resident.
__launch_bounds__(256, 3)
__global__ void p1_gemm_ctx(const float* __restrict__ hidden, const short* __restrict__ Bp,
                            short* __restrict__ h_att, float* __restrict__ ctx_part) {
    __shared__ __align__(16) short As[4][2][32 * 64];   // 32 KB, [wave][buf]

    int t = threadIdx.x;
    int wave = t >> 6, lane = t & 63, quad = lane >> 4, cb = lane & 15;
    int row0 = blockIdx.x * 128 + wave * 32;

    f32x4 acc[2][8];
    #pragma unroll
    for (int mt = 0; mt < 2; ++mt)
        #pragma unroll
        for (int nt = 0; nt < 8; ++nt)
            acc[mt][nt] = (f32x4){0.f, 0.f, 0.f, 0.f};

    int lrow = lane >> 4;      // 0..3
    int col4 = lane & 15;      // float4 index within 64-wide chunk
    const float* sbase = hidden + (size_t)(row0 + lrow) * HIDDEN + col4 * 4;
    short (*my)[32 * 64] = As[wave];
    const short8* Bp8 = (const short8*)Bp + lane;

    f32x4 g[8];

    auto issue_loads = [&](int c) {
        const float* src = sbase + c * 64;
        #pragma unroll
        for (int p = 0; p < 8; ++p)
            g[p] = nt_load4(src + (size_t)p * 4 * HIDDEN);
    };

    auto pack_write = [&](int c, int buf) {
        float s[4] = {0.f, 0.f, 0.f, 0.f};
        #pragma unroll
        for (int p = 0; p < 8; ++p) {
            int row = p * 4 + lrow;                 // 0..31 within wave tile
            const f32x4 f = g[p];
            s[0] += f.x; s[1] += f.y; s[2] += f.z; s[3] += f.w;
            ux2 pk;
            pk.x = pack2bf(f.x, f.y);
            pk.y = pack2bf(f.z, f.w);
            int off = row * 64 + (((col4 >> 1) ^ (row & 7)) << 3) + ((col4 & 1) << 2);
            *(ux2*)&my[buf][off] = pk;
        }
        #pragma unroll
        for (int j = 0; j < 4; ++j) {
            s[j] += __shfl_xor(s[j], 16);
            s[j] += __shfl_xor(s[j], 32);
        }
        if (lane < 16) {
            float* cp = ctx_part + (size_t)(blockIdx.x * 4 + wave) * HIDDEN + c * 64 + lane * 4;
            __builtin_nontemporal_store((f32x4){s[0], s[1], s[2], s[3]}, (f32x4*)cp);
        }
    };

    auto compute = [&](int c, int buf) {
        int swz = cb & 7;
        #pragma unroll
        for (int s2 = 0; s2 < 2; ++s2) {
            int ks = c * 2 + s2;
            // issue all 8 B loads up-front (L2 hits, nothing older outstanding)
            short8 b8[8];
            #pragma unroll
            for (int nt = 0; nt < 8; ++nt)
                b8[nt] = Bp8[((size_t)ks * 8 + nt) * 64];
            int blk = ((s2 * 4 + quad) ^ swz) << 3;
            short8 a0 = *(const short8*)&my[buf][cb * 64 + blk];
            short8 a1 = *(const short8*)&my[buf][(cb + 16) * 64 + blk];
            #pragma unroll
            for (int nt = 0; nt < 8; ++nt) {
                acc[0][nt] = __builtin_amdgcn_mfma_f32_16x16x32_bf16(a0, b8[nt], acc[0][nt], 0, 0, 0);
                acc[1][nt] = __builtin_amdgcn_mfma_f32_16x16x32_bf16(a1, b8[nt], acc[1][nt], 0, 0, 0);
            }
        }
    };

    issue_loads(0);
    pack_write(0, 0);
    for (int c = 0; c < 8; ++c) {
        compute(c, c & 1);                         // B(c) issued behind nothing
        if (c < 7) {
            issue_loads(c + 1);                    // A(c+1) issued AFTER B(c)
            pack_write(c + 1, (c + 1) & 1);        // waits A(c+1); B(c) already retired
        }
    }

    // epilogue: fragment-permuted coalesced store, bf16 pair-packed, nt
    ux2* hp = (ux2*)h_att;
    size_t base = (((size_t)blockIdx.x * 4 + wave) * 2) * 8 * 64 + lane;
    #pragma unroll
    for (int mt = 0; mt < 2; ++mt)
        #pragma unroll
        for (int nt = 0; nt < 8; ++nt) {
            ux2 p;
            p.x = pack2bf(acc[mt][nt][0], acc[mt][nt][1]);
            p.y = pack2bf(acc[mt][nt][2], acc[mt][nt][3]);
            __builtin_nontemporal_store(p, &hp[base + ((size_t)mt * 8 + nt) * 64]);
        }
}

// ---- P2: uatt[b][a] = (sum_chunks ctx_part / SL) . U[:,a] -----------------
__launch_bounds__(256)
__global__ void p2_uatt(const float* __restrict__ ctx_part, const float* __restrict__ U,
                        float* __restrict__ uatt) {
    int b = blockIdx.x, t = threadIdx.x;
    __shared__ float cs[HIDDEN];
    __shared__ float ds[256];
    float s0 = 0.f, s1 = 0.f;
    #pragma unroll 8
    for (int c = 0; c < 64; ++c) {
        const float* base = ctx_part + (size_t)(b * 64 + c) * HIDDEN;
        s0 += __builtin_nontemporal_load(base + t);
        s1 += __builtin_nontemporal_load(base + t + 256);
    }
    cs[t] = s0; cs[t + 256] = s1;
    __syncthreads();
    int a = t & 127, h0 = (t >> 7) * 256;
    float d = 0.f;
    #pragma unroll 8
    for (int h = 0; h < 256; ++h) d += cs[h0 + h] * U[(size_t)(h0 + h) * ATT + a];
    ds[t] = d;
    __syncthreads();
    if (t < 128) uatt[b * ATT + t] = (ds[t] + ds[t + 128]) * (1.f / SL);
}

// ---- P3: scores[r] = v . tanh(h_att[r] + uatt[b])  (fragment layout) ------
__launch_bounds__(256)
__global__ void p3_scores(const short* __restrict__ h_att, const float* __restrict__ v_a,
                          const float* __restrict__ uatt, float* __restrict__ scores) {
    int t = threadIdx.x, bx = blockIdx.x;
    int wave = t >> 6, lane = t & 63, quad = lane >> 4, cb = lane & 15;
    int b = bx >> 4;
    int row0 = bx * 128;

    float uv[8], vv[8];
    #pragma unroll
    for (int nt = 0; nt < 8; ++nt) {
        uv[nt] = uatt[b * ATT + nt * 16 + cb];
        vv[nt] = v_a[nt * 16 + cb];
    }

    const ux2* hp = (const ux2*)h_att;
    size_t base = (((size_t)bx * 4 + wave) * 2) * 8 * 64 + lane;

    #pragma unroll
    for (int mt = 0; mt < 2; ++mt) {
        ux2 f[8];
        #pragma unroll
        for (int nt = 0; nt < 8; ++nt)
            f[nt] = __builtin_nontemporal_load(&hp[base + ((size_t)mt * 8 + nt) * 64]);
        float r[4] = {0.f, 0.f, 0.f, 0.f};
        #pragma unroll
        for (int nt = 0; nt < 8; ++nt) {
            r[0] += vv[nt] * tanh_fast(bflo(f[nt].x) + uv[nt]);
            r[1] += vv[nt] * tanh_fast(bfhi(f[nt].x) + uv[nt]);
            r[2] += vv[nt] * tanh_fast(bflo(f[nt].y) + uv[nt]);
            r[3] += vv[nt] * tanh_fast(bfhi(f[nt].y) + uv[nt]);
        }
        #pragma unroll
        for (int j = 0; j < 4; ++j) {
            r[j] += __shfl_xor(r[j], 1);
            r[j] += __shfl_xor(r[j], 2);
            r[j] += __shfl_xor(r[j], 4);
            r[j] += __shfl_xor(r[j], 8);
        }
        if (cb == 0) {
            #pragma unroll
            for (int j = 0; j < 4; ++j)
                scores[row0 + wave * 32 + mt * 16 + quad * 4 + j] = r[j];
        }
    }
}

// ---- P4: softmax over L (in place, in d_out's attn region) ----------------
__launch_bounds__(256)
__global__ void p4_softmax(float* __restrict__ attn) {
    int b = blockIdx.x, t = threadIdx.x;
    float* p = attn + b * SL;
    __shared__ float red[256];
    float v[8];
    float m = -1e30f;
    #pragma unroll
    for (int i = 0; i < 8; ++i) { v[i] = p[t + i * 256]; m = fmaxf(m, v[i]); }
    red[t] = m; __syncthreads();
    for (int s = 128; s > 0; s >>= 1) { if (t < s) red[t] = fmaxf(red[t], red[t + s]); __syncthreads(); }
    m = red[0]; __syncthreads();
    float sum = 0.f;
    #pragma unroll
    for (int i = 0; i < 8; ++i) { v[i] = __expf(v[i] - m); sum += v[i]; }
    red[t] = sum; __syncthreads();
    for (int s = 128; s > 0; s >>= 1) { if (t < s) red[t] += red[t + s]; __syncthreads(); }
    float inv = 1.f / red[0];
    #pragma unroll
    for (int i = 0; i < 8; ++i) p[t + i * 256] = v[i] * inv;
}

// ---- P5: attended partials: att_part[c][b][h] = sum_{l in chunk} attn*h ----
__launch_bounds__(256)
__global__ void p5_attended(const float* __restrict__ hidden, const float* __restrict__ attn,
                            float* __restrict__ att_part) {
    int b = blockIdx.y, c = blockIdx.x, t = threadIdx.x;
    __shared__ float w_s[128];
    __shared__ f32x4 red_s[128];
    if (t < 128) w_s[t] = attn[b * SL + c * 128 + t];
    __syncthreads();
    int cg = t & 127, half = t >> 7;
    const float* hp = hidden + ((size_t)b * SL + c * 128 + half * 64) * HIDDEN + cg * 4;
    f32x4 a = {0.f, 0.f, 0.f, 0.f};
    #pragma unroll 4
    for (int l = 0; l < 64; ++l) {
        float w = w_s[half * 64 + l];
        const f32x4 g = nt_load4(hp + (size_t)l * HIDDEN);
        a.x += w * g.x; a.y += w * g.y; a.z += w * g.z; a.w += w * g.w;
    }
    if (half) red_s[cg] = a;
    __syncthreads();
    if (!half) {
        f32x4 r = red_s[cg];
        a.x += r.x; a.y += r.y; a.z += r.z; a.w += r.w;
        __builtin_nontemporal_store(a, (f32x4*)(att_part + ((size_t)(c * NB + b)) * HIDDEN + cg * 4));
    }
}

// ---- P6: reduce att_part chunks + LayerNorm -------------------------------
__launch_bounds__(256)
__global__ void p6_ln(const float* __restrict__ att_part, const float* __restrict__ gamma,
                      const float* __restrict__ beta, float* __restrict__ out) {
    int b = blockIdx.x, t = threadIdx.x;
    float x0 = 0.f, x1 = 0.f;
    #pragma unroll
    for (int c = 0; c < 16; ++c) {
        size_t base = (size_t)(c * NB + b) * HIDDEN;
        x0 += __builtin_nontemporal_load(att_part + base + t);
        x1 += __builtin_nontemporal_load(att_part + base + t + 256);
    }
    __shared__ float rs[256], rq[256];
    rs[t] = x0 + x1; rq[t] = x0 * x0 + x1 * x1;
    __syncthreads();
    for (int s = 128; s > 0; s >>= 1) {
        if (t < s) { rs[t] += rs[t + s]; rq[t] += rq[t + s]; }
        __syncthreads();
    }
    float mean = rs[0] * (1.f / HIDDEN);
    float var = rq[0] * (1.f / HIDDEN) - mean * mean;
    float r = rsqrtf(var + LN_EPS);
    out[b * HIDDEN + t]       = (x0 - mean) * r * gamma[t] + beta[t];
    out[b * HIDDEN + t + 256] = (x1 - mean) * r * gamma[t + 256] + beta[t + 256];
}

extern "C" void kernel_launch(void* const* d_in, const int* in_sizes, int n_in,
                              void* d_out, int out_size, void* d_ws, size_t ws_size,
                              hipStream_t stream) {
    const float* hidden = (const float*)d_in[0];
    const float* W      = (const float*)d_in[1];
    const float* U      = (const float*)d_in[2];
    const float* v_a    = (const float*)d_in[3];
    const float* gamma  = (const float*)d_in[4];
    const float* beta   = (const float*)d_in[5];

    float* out  = (float*)d_out;          // [64][512]
    float* attn = out + NB * HIDDEN;      // [64][2048] scores -> softmax in place

    // ws layout (every buffer fully written before read; no memset needed)
    short* h_att    = (short*)d_ws;                                        // [64*2048][128] bf16 (fragment-permuted)
    float* ctx_part = (float*)((char*)d_ws + (size_t)NB * SL * ATT * 2);   // [4096][512] per-wave
    float* att_part = ctx_part + (size_t)4096 * HIDDEN;                    // [16][64][512]
    float* uatt     = att_part + (size_t)16 * NB * HIDDEN;                 // [64][128]
    short* Bp       = (short*)(uatt + NB * ATT);                           // [16][8][64][8] bf16 (frag-permuted W)

    p0_wt<<<256, 256, 0, stream>>>(W, Bp);
    p1_gemm_ctx<<<(NB * SL) / 128, 256, 0, stream>>>(hidden, Bp, h_att, ctx_part);
    p2_uatt<<<NB, 256, 0, stream>>>(ctx_part, U, uatt);
    p3_scores<<<(NB * SL) / 128, 256, 0, stream>>>(h_att, v_a, uatt, attn);
    p4_softmax<<<NB, 256, 0, stream>>>(attn);
    p5_attended<<<dim3(16, NB), 256, 0, stream>>>(hidden, attn, att_part);
    p6_ln<<<NB, 256, 0, stream>>>(att_part, gamma, beta, out);
}